// Round 14
// baseline (41.071 us; speedup 1.0000x reference)
//
#include <hip/hip_runtime.h>

// SimpleUnsharedPatchScorer — register-run reduction, image-paired waves, per-wave bins.
// t = i*9408 + j*588 + c*196 + h*14 + w  (i,j in [0,16), c in [0,3), h,w in [0,14))
// value at t: x[b, c, 16h+i, 16w+j];  out bin p = t/768.
// R12 post-mortem: regression caused by bins shared across 7 waves whose h differ by
// <=84 -> identical p0 -> 7-way same-address LDS-atomic serialization. NOT the pairing.
// R14: same pairing (weight loaded once per 2 images, 75MB weight traffic) but per-wave
// private bins[wv][2][197] (11KB LDS) -> commit pattern identical to R9, just 2x count.

#define NPATCH 196
#define NF4IMG 37632     // float4s per image = 150528/4
#define BSTR   197       // LDS bin row stride

// prep (same as R9): wlay[((c*14+h)*14+w)*256 + i*16 + jj] = weight[t]; bias-init out.
__global__ __launch_bounds__(256) void prep_kernel(
    const float* __restrict__ weight,
    const float* __restrict__ bias,
    float* __restrict__ wlay,
    float* __restrict__ out)
{
    const int bid = blockIdx.x;
    if (bid < 147) {                          // 147*256*4 == 150528 weights
        const int t4 = bid * 256 + threadIdx.x;
        const float4 wv = ((const float4*)weight)[t4];
        const float wt[4] = {wv.x, wv.y, wv.z, wv.w};
        #pragma unroll
        for (int u = 0; u < 4; ++u) {
            const int t    = 4 * t4 + u;
            const int i    = t / 9408;
            const int rem  = t - i * 9408;
            const int jj   = rem / 588;
            const int rem2 = rem - jj * 588;
            const int c    = rem2 / 196;
            const int rem3 = rem2 - c * 196;
            const int h    = rem3 / 14;
            const int w    = rem3 - h * 14;
            wlay[((c * 14 + h) * 14 + w) * 256 + i * 16 + jj] = wt[u];
        }
    } else {                                  // 49*256*4 == 50176 == 256*196 bias-init
        const int g4 = (bid - 147) * 256 + threadIdx.x;
        const int g  = 4 * g4;
        float4 o;
        o.x = bias[(g + 0) % NPATCH];
        o.y = bias[(g + 1) % NPATCH];
        o.z = bias[(g + 2) % NPATCH];
        o.w = bias[(g + 3) % NPATCH];
        ((float4*)out)[g4] = o;
    }
}

__global__ __launch_bounds__(448) void run_kernel(
    const float* __restrict__ x,     // [256,3,224,224]
    const float* __restrict__ wlay,  // permuted weights (602112 floats)
    float* __restrict__ out)         // [256,196], bias pre-loaded
{
    __shared__ float bins[7 * 2 * BSTR];      // per-wave, per-image bin rows
    const int tid  = threadIdx.x;
    const int r    = blockIdx.x & 255;
    const int c    = blockIdx.x >> 8;         // channel 0..2
    const int hh   = r & 1;                   // h half
    const int b0   = (r >> 1) * 2;            // image pair base
    const int wv   = tid >> 6;                // wave 0..6
    const int lane = tid & 63;
    const int i    = lane >> 2;
    const int j4   = lane & 3;                // j = 4*j4 + dj
    const int h    = hh * 7 + wv;
    const int tile = c * 14 + h;

    for (int k = tid; k < 7 * 2 * BSTR; k += 448) bins[k] = 0.0f;
    __syncthreads();

    float* mybins = bins + wv * 2 * BSTR;     // [2][BSTR] private to this wave

    const float4* __restrict__ x40 = (const float4*)x + (size_t)b0 * NF4IMG
                                     + c * 12544 + (16 * h + i) * 56 + j4;
    const float4* __restrict__ x41 = x40 + NF4IMG;
    const float4* __restrict__ w4  = (const float4*)wlay + tile * 896 + i * 4 + j4;

    int p0[4], ws_[4];
    #pragma unroll
    for (int u = 0; u < 4; ++u) {
        const int jj = 4 * j4 + u;
        const int t0 = i * 9408 + jj * 588 + c * 196 + h * 14;
        p0[u]  = t0 / 768;
        ws_[u] = 768 * (p0[u] + 1) - t0;      // w >= ws_ -> bin p0+1 (ws_=14 => no split)
    }

    float accA0[4] = {0.f, 0.f, 0.f, 0.f}, accB0[4] = {0.f, 0.f, 0.f, 0.f};
    float accA1[4] = {0.f, 0.f, 0.f, 0.f}, accB1[4] = {0.f, 0.f, 0.f, 0.f};

    #pragma unroll
    for (int w = 0; w < 14; ++w) {
        const float4 wv_ = w4[64 * w];        // one weight load serves both images
        const float4 xv0 = x40[4 * w];
        const float4 xv1 = x41[4 * w];
        const float wsv[4] = {wv_.x, wv_.y, wv_.z, wv_.w};
        const float xs0[4] = {xv0.x, xv0.y, xv0.z, xv0.w};
        const float xs1[4] = {xv1.x, xv1.y, xv1.z, xv1.w};
        #pragma unroll
        for (int u = 0; u < 4; ++u) {
            const float sel = (w < ws_[u]) ? 1.0f : 0.0f;
            const float v0  = xs0[u] * wsv[u];
            const float v1  = xs1[u] * wsv[u];
            accA0[u] = fmaf(v0, sel, accA0[u]);
            accB0[u] = fmaf(v0, 1.0f - sel, accB0[u]);
            accA1[u] = fmaf(v1, sel, accA1[u]);
            accB1[u] = fmaf(v1, 1.0f - sel, accB1[u]);
        }
    }

    #pragma unroll
    for (int u = 0; u < 4; ++u) {
        unsafeAtomicAdd(&mybins[p0[u]], accA0[u]);                 // ds_add_f32, img 0
        unsafeAtomicAdd(&mybins[BSTR + p0[u]], accA1[u]);          // img 1
        if (ws_[u] < 14) {
            unsafeAtomicAdd(&mybins[p0[u] + 1], accB0[u]);         // rare split (~1.7%)
            unsafeAtomicAdd(&mybins[BSTR + p0[u] + 1], accB1[u]);
        }
    }
    __syncthreads();

    // 7-way tree sum per (img, p), then one device atomic each: 768*392 ~= 301K total
    for (int k = tid; k < 2 * NPATCH; k += 448) {
        const int img = k / NPATCH;
        const int p   = k - img * NPATCH;
        float s = 0.0f;
        #pragma unroll
        for (int v = 0; v < 7; ++v) s += bins[v * 2 * BSTR + img * BSTR + p];
        unsafeAtomicAdd(&out[(b0 + img) * NPATCH + p], s);
    }
}

extern "C" void kernel_launch(void* const* d_in, const int* in_sizes, int n_in,
                              void* d_out, int out_size, void* d_ws, size_t ws_size,
                              hipStream_t stream) {
    const float* x      = (const float*)d_in[0];
    const float* weight = (const float*)d_in[1];
    const float* bias   = (const float*)d_in[2];
    float* out          = (float*)d_out;
    float* wlay         = (float*)d_ws;      // 602112 bytes

    prep_kernel<<<196, 256, 0, stream>>>(weight, bias, wlay, out);
    run_kernel<<<768, 448, 0, stream>>>(x, wlay, out);
}

// Round 16
// 35.930 us; speedup vs baseline: 1.1431x; 1.1431x over previous
//
#include <hip/hip_runtime.h>

// SimpleUnsharedPatchScorer — register-run reduction, h-split blocks. (R9 champion, reverted)
// t = i*9408 + j*588 + c*196 + h*14 + w  (i,j in [0,16), c in [0,3), h,w in [0,14))
// value at t: x[b, c, 16h+i, 16w+j];  out bin p = t/768.
// Experiment ledger: R10/R11 (128B lane map) neutral; R12-R14 (image pairing, both bin
// topologies) regressed -> weight-L2-contention theory refuted; R9 structure is the floor:
// ~29us run (x read-once + L3 assist) + ~2.5us prep + launch/tail. Keep R9.

#define NPATCH 196
#define NF4IMG 37632     // float4s per image = 150528/4
#define BSTR   197       // LDS bin row stride

// prep: bid<147: wlay permute (coalesced weight float4 read, scattered stores);
//       bid>=147: out[g] = bias[g%196] (coalesced float4 store).
__global__ __launch_bounds__(256) void prep_kernel(
    const float* __restrict__ weight,
    const float* __restrict__ bias,
    float* __restrict__ wlay,
    float* __restrict__ out)
{
    const int bid = blockIdx.x;
    if (bid < 147) {                          // 147*256*4 == 150528 weights
        const int t4 = bid * 256 + threadIdx.x;
        const float4 wv = ((const float4*)weight)[t4];
        const float wt[4] = {wv.x, wv.y, wv.z, wv.w};
        #pragma unroll
        for (int u = 0; u < 4; ++u) {
            const int t    = 4 * t4 + u;
            const int i    = t / 9408;
            const int rem  = t - i * 9408;
            const int jj   = rem / 588;
            const int rem2 = rem - jj * 588;
            const int c    = rem2 / 196;
            const int rem3 = rem2 - c * 196;
            const int h    = rem3 / 14;
            const int w    = rem3 - h * 14;
            wlay[((c * 14 + h) * 14 + w) * 256 + i * 16 + jj] = wt[u];
        }
    } else {                                  // 49*256*4 == 50176 == 256*196 bias-init
        const int g4 = (bid - 147) * 256 + threadIdx.x;
        const int g  = 4 * g4;
        float4 o;
        o.x = bias[(g + 0) % NPATCH];
        o.y = bias[(g + 1) % NPATCH];
        o.z = bias[(g + 2) % NPATCH];
        o.w = bias[(g + 3) % NPATCH];
        ((float4*)out)[g4] = o;
    }
}

__global__ __launch_bounds__(448) void run_kernel(
    const float* __restrict__ x,     // [256,3,224,224]
    const float* __restrict__ wlay,  // permuted weights (602112 floats)
    float* __restrict__ out)         // [256,196], bias pre-loaded
{
    __shared__ float bins[7 * BSTR];
    const int tid  = threadIdx.x;
    const int b    = blockIdx.x >> 1;         // image
    const int hh   = blockIdx.x & 1;          // h half
    const int wv   = tid >> 6;                // wave 0..6
    const int lane = tid & 63;
    const int i    = lane >> 2;
    const int j4   = lane & 3;                // j = 4*j4 + dj
    const int h    = hh * 7 + wv;

    for (int k = tid; k < 7 * BSTR; k += 448) bins[k] = 0.0f;
    __syncthreads();

    float* mybins = bins + wv * BSTR;

    #pragma unroll
    for (int c = 0; c < 3; ++c) {
        const int tile = c * 14 + h;
        const float4* __restrict__ x4 = (const float4*)x + (size_t)b * NF4IMG
                                        + c * 12544 + (16 * h + i) * 56 + j4;
        const float4* __restrict__ w4 = (const float4*)wlay + tile * 896 + i * 4 + j4;

        int p0[4], ws_[4];
        #pragma unroll
        for (int dj = 0; dj < 4; ++dj) {
            const int jj = 4 * j4 + dj;
            const int t0 = i * 9408 + jj * 588 + c * 196 + h * 14;
            p0[dj]  = t0 / 768;
            ws_[dj] = 768 * (p0[dj] + 1) - t0;   // w >= ws_ -> bin p0+1 (ws_=14 => no split)
        }

        float accA[4] = {0.f, 0.f, 0.f, 0.f};
        float accB[4] = {0.f, 0.f, 0.f, 0.f};
        #pragma unroll
        for (int w = 0; w < 14; ++w) {
            const float4 xv  = x4[4 * w];
            const float4 wv_ = w4[64 * w];
            const float xs[4]  = {xv.x, xv.y, xv.z, xv.w};
            const float wsv[4] = {wv_.x, wv_.y, wv_.z, wv_.w};
            #pragma unroll
            for (int dj = 0; dj < 4; ++dj) {
                const float v   = xs[dj] * wsv[dj];
                const float sel = (w < ws_[dj]) ? 1.0f : 0.0f;
                accA[dj] = fmaf(v, sel, accA[dj]);
                accB[dj] = fmaf(v, 1.0f - sel, accB[dj]);
            }
        }

        #pragma unroll
        for (int dj = 0; dj < 4; ++dj) {
            unsafeAtomicAdd(&mybins[p0[dj]], accA[dj]);          // ds_add_f32, per-wave row
            if (ws_[dj] < 14)
                unsafeAtomicAdd(&mybins[p0[dj] + 1], accB[dj]);  // rare split (~1.7%)
        }
    }
    __syncthreads();

    // 7-way tree sum, then one device atomic per (block, p): 196*512 ~= 100K total
    for (int p = tid; p < NPATCH; p += 448) {
        float s = 0.0f;
        #pragma unroll
        for (int k = 0; k < 7; ++k) s += bins[k * BSTR + p];
        unsafeAtomicAdd(&out[b * NPATCH + p], s);
    }
}

extern "C" void kernel_launch(void* const* d_in, const int* in_sizes, int n_in,
                              void* d_out, int out_size, void* d_ws, size_t ws_size,
                              hipStream_t stream) {
    const float* x      = (const float*)d_in[0];
    const float* weight = (const float*)d_in[1];
    const float* bias   = (const float*)d_in[2];
    float* out          = (float*)d_out;
    float* wlay         = (float*)d_ws;      // 602112 bytes

    prep_kernel<<<196, 256, 0, stream>>>(weight, bias, wlay, out);
    run_kernel<<<512, 448, 0, stream>>>(x, wlay, out);
}

// Round 17
// 33.176 us; speedup vs baseline: 1.2380x; 1.0830x over previous
//
#include <hip/hip_runtime.h>
#include <hip/hip_bf16.h>

// SimpleUnsharedPatchScorer — register-run reduction, h-split blocks, bf16 wlay.
// t = i*9408 + j*588 + c*196 + h*14 + w  (i,j in [0,16), c in [0,3), h,w in [0,14))
// value at t: x[b, c, 16h+i, 16w+j];  out bin p = t/768.
// Ledger: R10/R11 lane map neutral; R12-R14 pairing regressed (confounded); R16 confirms
// R9 at 35.93us. R17: ONLY change = wlay stored bf16 (RNE) -> weight L2 traffic halved
// (294->147 KB/block) with identical grid/loop/bins/atomics. Clean weight-bytes A/B.

#define NPATCH 196
#define NF4IMG 37632     // float4s per image = 150528/4
#define BSTR   197       // LDS bin row stride

__device__ __forceinline__ float bf2f(unsigned short s) {
    return __uint_as_float((unsigned int)s << 16);
}

// prep: bid<147: wlay[(tile*14+w)*256 + i*16 + jj] = bf16(weight[t]) (coalesced read);
//       bid>=147: out[g] = bias[g%196] (coalesced float4 store).
__global__ __launch_bounds__(256) void prep_kernel(
    const float* __restrict__ weight,
    const float* __restrict__ bias,
    __hip_bfloat16* __restrict__ wlay,
    float* __restrict__ out)
{
    const int bid = blockIdx.x;
    if (bid < 147) {                          // 147*256*4 == 150528 weights
        const int t4 = bid * 256 + threadIdx.x;
        const float4 wv = ((const float4*)weight)[t4];
        const float wt[4] = {wv.x, wv.y, wv.z, wv.w};
        #pragma unroll
        for (int u = 0; u < 4; ++u) {
            const int t    = 4 * t4 + u;
            const int i    = t / 9408;
            const int rem  = t - i * 9408;
            const int jj   = rem / 588;
            const int rem2 = rem - jj * 588;
            const int c    = rem2 / 196;
            const int rem3 = rem2 - c * 196;
            const int h    = rem3 / 14;
            const int w    = rem3 - h * 14;
            wlay[((c * 14 + h) * 14 + w) * 256 + i * 16 + jj] = __float2bfloat16(wt[u]);
        }
    } else {                                  // 49*256*4 == 50176 == 256*196 bias-init
        const int g4 = (bid - 147) * 256 + threadIdx.x;
        const int g  = 4 * g4;
        float4 o;
        o.x = bias[(g + 0) % NPATCH];
        o.y = bias[(g + 1) % NPATCH];
        o.z = bias[(g + 2) % NPATCH];
        o.w = bias[(g + 3) % NPATCH];
        ((float4*)out)[g4] = o;
    }
}

__global__ __launch_bounds__(448) void run_kernel(
    const float* __restrict__ x,              // [256,3,224,224]
    const __hip_bfloat16* __restrict__ wlay,  // permuted bf16 weights (150528)
    float* __restrict__ out)                  // [256,196], bias pre-loaded
{
    __shared__ float bins[7 * BSTR];
    const int tid  = threadIdx.x;
    const int b    = blockIdx.x >> 1;         // image
    const int hh   = blockIdx.x & 1;          // h half
    const int wv   = tid >> 6;                // wave 0..6
    const int lane = tid & 63;
    const int i    = lane >> 2;
    const int j4   = lane & 3;                // j = 4*j4 + dj
    const int h    = hh * 7 + wv;

    for (int k = tid; k < 7 * BSTR; k += 448) bins[k] = 0.0f;
    __syncthreads();

    float* mybins = bins + wv * BSTR;

    #pragma unroll
    for (int c = 0; c < 3; ++c) {
        const int tile = c * 14 + h;
        const float4* __restrict__ x4 = (const float4*)x + (size_t)b * NF4IMG
                                        + c * 12544 + (16 * h + i) * 56 + j4;
        const ushort4* __restrict__ w4 = (const ushort4*)wlay + tile * 896 + i * 4 + j4;

        int p0[4], ws_[4];
        #pragma unroll
        for (int dj = 0; dj < 4; ++dj) {
            const int jj = 4 * j4 + dj;
            const int t0 = i * 9408 + jj * 588 + c * 196 + h * 14;
            p0[dj]  = t0 / 768;
            ws_[dj] = 768 * (p0[dj] + 1) - t0;   // w >= ws_ -> bin p0+1 (ws_=14 => no split)
        }

        float accA[4] = {0.f, 0.f, 0.f, 0.f};
        float accB[4] = {0.f, 0.f, 0.f, 0.f};
        #pragma unroll
        for (int w = 0; w < 14; ++w) {
            const float4  xv  = x4[4 * w];
            const ushort4 wv_ = w4[64 * w];       // 8B: 4 bf16 weights
            const float xs[4]  = {xv.x, xv.y, xv.z, xv.w};
            const float wsv[4] = {bf2f(wv_.x), bf2f(wv_.y), bf2f(wv_.z), bf2f(wv_.w)};
            #pragma unroll
            for (int dj = 0; dj < 4; ++dj) {
                const float v   = xs[dj] * wsv[dj];
                const float sel = (w < ws_[dj]) ? 1.0f : 0.0f;
                accA[dj] = fmaf(v, sel, accA[dj]);
                accB[dj] = fmaf(v, 1.0f - sel, accB[dj]);
            }
        }

        #pragma unroll
        for (int dj = 0; dj < 4; ++dj) {
            unsafeAtomicAdd(&mybins[p0[dj]], accA[dj]);          // ds_add_f32, per-wave row
            if (ws_[dj] < 14)
                unsafeAtomicAdd(&mybins[p0[dj] + 1], accB[dj]);  // rare split (~1.7%)
        }
    }
    __syncthreads();

    // 7-way tree sum, then one device atomic per (block, p): 196*512 ~= 100K total
    for (int p = tid; p < NPATCH; p += 448) {
        float s = 0.0f;
        #pragma unroll
        for (int k = 0; k < 7; ++k) s += bins[k * BSTR + p];
        unsafeAtomicAdd(&out[b * NPATCH + p], s);
    }
}

extern "C" void kernel_launch(void* const* d_in, const int* in_sizes, int n_in,
                              void* d_out, int out_size, void* d_ws, size_t ws_size,
                              hipStream_t stream) {
    const float* x      = (const float*)d_in[0];
    const float* weight = (const float*)d_in[1];
    const float* bias   = (const float*)d_in[2];
    float* out          = (float*)d_out;
    __hip_bfloat16* wlay = (__hip_bfloat16*)d_ws;   // 301056 bytes

    prep_kernel<<<196, 256, 0, stream>>>(weight, bias, wlay, out);
    run_kernel<<<512, 448, 0, stream>>>(x, wlay, out);
}